// Round 2
// baseline (1561.716 us; speedup 1.0000x reference)
//
#include <hip/hip_runtime.h>
#include <hip/hip_bf16.h>

using bf16 = __hip_bfloat16;
typedef __attribute__((ext_vector_type(8))) short short8;
typedef __attribute__((ext_vector_type(4))) float f32x4;

#define MFMA(a,b,c) __builtin_amdgcn_mfma_f32_16x16x32_bf16(a, b, c, 0, 0, 0)

#define B_      128
#define C_      1024
#define NH      8
#define HD      128
#define HW      24
#define NTOK    576
#define QH      12
#define QN      144

static __device__ __forceinline__ float bf2f(bf16 v) { return __bfloat162float(v); }
static __device__ __forceinline__ bf16  f2bf(float v) { return __float2bfloat16(v); }
static __device__ __forceinline__ float s2f(short s) {
    return __uint_as_float(((unsigned)(unsigned short)s) << 16);
}

__device__ __forceinline__ void gll16(const bf16* src, bf16* dst_lds) {
    __builtin_amdgcn_global_load_lds(
        (__attribute__((address_space(1))) const unsigned int*)src,
        (__attribute__((address_space(3))) unsigned int*)dst_lds,
        16, 0, 0);
}

// ---------------- transpose + fp32->bf16 convert: out[c][r] = in[r][c] ----------------
__global__ __launch_bounds__(256) void transpose_cvt(
    const float* __restrict__ in, bf16* __restrict__ out,
    int R, int Ccols, size_t ibs, size_t obs)
{
    __shared__ float tile[32][33];
    const float* ib = in + (size_t)blockIdx.z * ibs;
    bf16* ob = out + (size_t)blockIdx.z * obs;
    int c0 = blockIdx.x * 32, r0 = blockIdx.y * 32;
    int tx = threadIdx.x & 31, ty = threadIdx.x >> 5;
    #pragma unroll
    for (int i = 0; i < 32; i += 8)
        tile[ty + i][tx] = ib[(size_t)(r0 + ty + i) * Ccols + c0 + tx];
    __syncthreads();
    #pragma unroll
    for (int i = 0; i < 32; i += 8)
        ob[(size_t)(c0 + ty + i) * R + r0 + tx] = f2bf(tile[tx][ty + i]);
}

// ---------------- 3x3 s2 avg pool (count_include_pad), xt[B*N][C] -> xp[B*qN][C] ------
__global__ __launch_bounds__(256) void pool_kernel(const bf16* __restrict__ xt,
                                                   bf16* __restrict__ xp)
{
    int bqn = blockIdx.x;
    int b = bqn / QN, qn = bqn % QN;
    int y = qn / QH, x = qn % QH;
    int t = threadIdx.x;
    float s0 = 0, s1 = 0, s2 = 0, s3 = 0;
    for (int dy = 0; dy < 3; dy++) {
        int hy = 2 * y - 1 + dy;
        if (hy < 0 || hy >= HW) continue;
        for (int dx = 0; dx < 3; dx++) {
            int hx = 2 * x - 1 + dx;
            if (hx < 0 || hx >= HW) continue;
            const bf16* row = xt + (size_t)(b * NTOK + hy * HW + hx) * C_;
            s0 += bf2f(row[t]);
            s1 += bf2f(row[t + 256]);
            s2 += bf2f(row[t + 512]);
            s3 += bf2f(row[t + 768]);
        }
    }
    bf16* o = xp + (size_t)bqn * C_;
    const float n = 1.f / 9.f;
    o[t] = f2bf(s0 * n); o[t + 256] = f2bf(s1 * n);
    o[t + 512] = f2bf(s2 * n); o[t + 768] = f2bf(s3 * n);
}

// ---------------- NT GEMM: C[m][n] = sum_k A[m][k]*Bt[n][k], K=1024 -------------------
template<int EPI>
__global__ __launch_bounds__(256, 2) void gemm_nt(
    const bf16* __restrict__ A, const bf16* __restrict__ Bt,
    void* __restrict__ Cout, const float* __restrict__ bias)
{
    __shared__ bf16 lds[2][2][128 * 64];
    const int tid = threadIdx.x;
    const int wv = tid >> 6, ln = tid & 63;
    const int m0 = blockIdx.x * 128, n0 = blockIdx.y * 128;
    const int wr = wv >> 1, wc = wv & 1;
    const int l15 = ln & 15, l4 = ln >> 4;
    const int r8 = ln >> 3, sl = ln & 7;
    const int sg = sl ^ r8;

    const bf16* gA = A + (size_t)m0 * C_;
    const bf16* gB = Bt + (size_t)n0 * C_;

    f32x4 zero = {0.f, 0.f, 0.f, 0.f};
    f32x4 acc[4][4];
    #pragma unroll
    for (int i = 0; i < 4; i++)
        #pragma unroll
        for (int j = 0; j < 4; j++) acc[i][j] = zero;

    auto stage = [&](int kt, int d) {
        const bf16* sa = gA + kt * 64;
        const bf16* sb = gB + kt * 64;
        bf16* la = lds[d][0];
        bf16* lb = lds[d][1];
        #pragma unroll
        for (int i = 0; i < 4; i++) {
            int chunk = wv * 4 + i;
            gll16(sa + (size_t)(chunk * 8 + r8) * C_ + sg * 8, la + chunk * 512);
            gll16(sb + (size_t)(chunk * 8 + r8) * C_ + sg * 8, lb + chunk * 512);
        }
    };

    stage(0, 0);
    asm volatile("s_waitcnt vmcnt(0)");
    __syncthreads();

    int cur = 0;
    for (int kt = 0; kt < 16; kt++) {
        if (kt < 15) stage(kt + 1, cur ^ 1);
        const bf16* la = lds[cur][0];
        const bf16* lb = lds[cur][1];
        #pragma unroll
        for (int ks = 0; ks < 2; ks++) {
            short8 af[4], bfr[4];
            #pragma unroll
            for (int fm = 0; fm < 4; fm++) {
                int row = wr * 64 + fm * 16 + l15;
                int slot = (ks * 4 + l4) ^ (row & 7);
                af[fm] = *(const short8*)((const char*)la + row * 128 + slot * 16);
            }
            #pragma unroll
            for (int fn = 0; fn < 4; fn++) {
                int row = wc * 64 + fn * 16 + l15;
                int slot = (ks * 4 + l4) ^ (row & 7);
                bfr[fn] = *(const short8*)((const char*)lb + row * 128 + slot * 16);
            }
            #pragma unroll
            for (int fm = 0; fm < 4; fm++)
                #pragma unroll
                for (int fn = 0; fn < 4; fn++)
                    acc[fm][fn] = MFMA(af[fm], bfr[fn], acc[fm][fn]);
        }
        asm volatile("s_waitcnt vmcnt(0)");
        __syncthreads();
        cur ^= 1;
    }

    #pragma unroll
    for (int fm = 0; fm < 4; fm++) {
        #pragma unroll
        for (int fn = 0; fn < 4; fn++) {
            #pragma unroll
            for (int r = 0; r < 4; r++) {
                int row = m0 + wr * 64 + fm * 16 + l4 * 4 + r;
                int col = n0 + wc * 64 + fn * 16 + l15;
                float v = acc[fm][fn][r];
                if constexpr (EPI == 0) {
                    ((bf16*)Cout)[(size_t)row * C_ + col] = f2bf(v);
                } else if constexpr (EPI == 1) {
                    int bb = col / NTOK, nn = col % NTOK;
                    ((bf16*)Cout)[((size_t)bb * C_ + row) * NTOK + nn] = f2bf(v);
                } else {
                    int bb = col / QN, qn = col % QN;
                    ((float*)Cout)[(size_t)bb * (C_ * QN) + (size_t)row * QN + qn] =
                        v + bias[row];
                }
            }
        }
    }
}

// ---------------- fused pooled-Q attention ---------------------------------------------
// grid: B*NH*3 blocks; block = 48 q-rows of one (b,h); 3 waves x 16 q-rows.
__global__ __launch_bounds__(192, 3) void attn_kernel(
    const bf16* __restrict__ qbuf, const bf16* __restrict__ kbuf,
    const bf16* __restrict__ vt, const float* __restrict__ rph,
    const float* __restrict__ rpw, bf16* __restrict__ attno)
{
    __shared__ float relh[48 * 24];
    __shared__ float relw[48 * 24];
    __shared__ char  plds[3][16 * 128];

    const int bid = blockIdx.x;
    const int b = bid / 24;
    const int rem = bid - b * 24;
    const int h = rem / 3, qblk = rem - (rem / 3) * 3;
    const int w = threadIdx.x >> 6, ln = threadIdx.x & 63;
    const int l15 = ln & 15, l4 = ln >> 4;
    const int row0 = qblk * 48;                 // block's first q-row

    const bf16* qbase = qbuf + ((size_t)(b * QN + row0 + w * 16) * C_ + h * HD);
    const bf16* kbase = kbuf + ((size_t)b * NTOK * C_ + h * HD);
    const bf16* vbase = vt + (size_t)(b * C_ + h * HD) * NTOK;

    // relative-position bias tables for the block's 48 rows
    for (int i = threadIdx.x; i < 48 * 24; i += 192) {
        int qr = i / 24, kk = i - qr * 24;
        int qg = row0 + qr;
        int y = qg / 12, x = qg - y * 12;
        const short8* q8 = (const short8*)(qbuf + ((size_t)(b * QN + qg) * C_ + h * HD));
        const f32x4* rh = (const f32x4*)(rph + (2 * y - kk + 23) * HD);
        const f32x4* rw = (const f32x4*)(rpw + (2 * x - kk + 23) * HD);
        float sh = 0.f, sw = 0.f;
        for (int c0 = 0; c0 < 16; c0++) {
            short8 qv = q8[c0];
            f32x4 h0 = rh[c0 * 2], h1 = rh[c0 * 2 + 1];
            f32x4 w0 = rw[c0 * 2], w1 = rw[c0 * 2 + 1];
            #pragma unroll
            for (int j = 0; j < 4; j++) {
                sh = fmaf(s2f(qv[j]), h0[j], sh);
                sw = fmaf(s2f(qv[j]), w0[j], sw);
                sh = fmaf(s2f(qv[j + 4]), h1[j], sh);
                sw = fmaf(s2f(qv[j + 4]), w1[j], sw);
            }
        }
        relh[i] = sh;
        relw[i] = sw;
    }
    __syncthreads();

    // persistent q fragments (A-operand layout), 16 rows per wave
    short8 qfr[4];
    #pragma unroll
    for (int ks = 0; ks < 4; ks++)
        qfr[ks] = *(const short8*)(qbase + (size_t)l15 * C_ + ks * 32 + l4 * 8);

    f32x4 zero = {0.f, 0.f, 0.f, 0.f};
    f32x4 Of[8];
    float mrun[4], lrun[4];
    #pragma unroll
    for (int hf = 0; hf < 8; hf++) Of[hf] = zero;
    #pragma unroll
    for (int r = 0; r < 4; r++) { mrun[r] = -1e30f; lrun[r] = 0.f; }

    const float scale = 0.08838834764831845f;  // 1/sqrt(128)
    const int rbase = (w * 16 + l4 * 4) * 24;  // rel-table row base for this thread

    for (int kt = 0; kt < 9; kt++) {
        // S = q @ k^T  (16 x 64 per wave)
        f32x4 S[4];
        #pragma unroll
        for (int kf = 0; kf < 4; kf++) {
            short8 bfr[4];
            #pragma unroll
            for (int ks = 0; ks < 4; ks++)
                bfr[ks] = *(const short8*)(kbase + (size_t)(kt * 64 + kf * 16 + l15) * C_ +
                                           ks * 32 + l4 * 8);
            f32x4 acc = zero;
            #pragma unroll
            for (int ks = 0; ks < 4; ks++) acc = MFMA(qfr[ks], bfr[ks], acc);
            S[kf] = acc;
        }
        // scale + rel-pos bias
        #pragma unroll
        for (int kf = 0; kf < 4; kf++) {
            int key = kt * 64 + kf * 16 + l15;
            int kr = key / 24, kc = key - kr * 24;
            #pragma unroll
            for (int r = 0; r < 4; r++)
                S[kf][r] = S[kf][r] * scale + relh[rbase + r * 24 + kr] +
                           relw[rbase + r * 24 + kc];
        }
        // online softmax (rows live in 16-lane groups)
        float alpha[4];
        #pragma unroll
        for (int r = 0; r < 4; r++) {
            float mt = fmaxf(fmaxf(S[0][r], S[1][r]), fmaxf(S[2][r], S[3][r]));
            #pragma unroll
            for (int d = 1; d < 16; d <<= 1) mt = fmaxf(mt, __shfl_xor(mt, d, 64));
            float mn = fmaxf(mrun[r], mt);
            alpha[r] = __expf(mrun[r] - mn);
            mrun[r] = mn;
            float ps = 0.f;
            #pragma unroll
            for (int kf = 0; kf < 4; kf++) {
                float p = __expf(S[kf][r] - mn);
                S[kf][r] = p;
                ps += p;
            }
            #pragma unroll
            for (int d = 1; d < 16; d <<= 1) ps += __shfl_xor(ps, d, 64);
            lrun[r] = lrun[r] * alpha[r] + ps;
        }
        // rescale O
        #pragma unroll
        for (int hf = 0; hf < 8; hf++)
            #pragma unroll
            for (int r = 0; r < 4; r++) Of[hf][r] *= alpha[r];
        // P -> LDS (bf16, XOR-swizzled 128B rows)
        #pragma unroll
        for (int kf = 0; kf < 4; kf++) {
            int key = kf * 16 + l15;
            int slotb = key >> 3, kin = key & 7;
            #pragma unroll
            for (int r = 0; r < 4; r++) {
                int row = l4 * 4 + r;
                int byt = row * 128 + ((slotb ^ (row & 7)) << 4) + kin * 2;
                *(bf16*)(&plds[w][byt]) = f2bf(S[kf][r]);
            }
        }
        // PV: O += P @ V
        #pragma unroll
        for (int ks2 = 0; ks2 < 2; ks2++) {
            int prow = l15;
            int slot = (ks2 * 4 + l4) ^ (prow & 7);
            short8 pa = *(const short8*)(&plds[w][prow * 128 + slot * 16]);
            #pragma unroll
            for (int hf = 0; hf < 8; hf++) {
                short8 vb = *(const short8*)(vbase + (size_t)(hf * 16 + l15) * NTOK +
                                             kt * 64 + ks2 * 32 + l4 * 8);
                Of[hf] = MFMA(pa, vb, Of[hf]);
            }
        }
    }

    // epilogue: O/l + q residual
    bf16* obase = attno + ((size_t)(b * QN + row0 + w * 16) * C_ + h * HD);
    #pragma unroll
    for (int r = 0; r < 4; r++) {
        int qr = l4 * 4 + r;
        float inv = 1.f / lrun[r];
        #pragma unroll
        for (int hf = 0; hf < 8; hf++) {
            int hd = hf * 16 + l15;
            float o = Of[hf][r] * inv + bf2f(qbase[(size_t)qr * C_ + hd]);
            obase[(size_t)qr * C_ + hd] = f2bf(o);
        }
    }
}

extern "C" void kernel_launch(void* const* d_in, const int* in_sizes, int n_in,
                              void* d_out, int out_size, void* d_ws, size_t ws_size,
                              hipStream_t stream)
{
    const float* x   = (const float*)d_in[0];
    const float* Wq  = (const float*)d_in[1];
    const float* Wk  = (const float*)d_in[2];
    const float* Wv  = (const float*)d_in[3];
    const float* Wp  = (const float*)d_in[4];
    const float* bp  = (const float*)d_in[5];
    const float* rph = (const float*)d_in[6];
    const float* rpw = (const float*)d_in[7];

    char* ws = (char*)d_ws;
    const size_t MB = 1024 * 1024;
    bf16* Wqt  = (bf16*)(ws + 0 * MB);
    bf16* Wkt  = (bf16*)(ws + 2 * MB);
    bf16* Wvt  = (bf16*)(ws + 4 * MB);
    bf16* Wpt  = (bf16*)(ws + 6 * MB);
    bf16* xt   = (bf16*)(ws + 8 * MB);          // 144 MB, reused as attno
    bf16* kbuf = (bf16*)(ws + 152 * MB);        // 144 MB
    bf16* vtb  = (bf16*)(ws + 296 * MB);        // 144 MB
    bf16* xp   = (bf16*)(ws + 440 * MB);        // 36 MB
    bf16* qbuf = (bf16*)(ws + 476 * MB);        // 36 MB -> end 512 MB
    bf16* attno = xt;

    transpose_cvt<<<dim3(32, 32, 1), 256, 0, stream>>>(Wq, Wqt, 1024, 1024, 0, 0);
    transpose_cvt<<<dim3(32, 32, 1), 256, 0, stream>>>(Wk, Wkt, 1024, 1024, 0, 0);
    transpose_cvt<<<dim3(32, 32, 1), 256, 0, stream>>>(Wv, Wvt, 1024, 1024, 0, 0);
    transpose_cvt<<<dim3(32, 32, 1), 256, 0, stream>>>(Wp, Wpt, 1024, 1024, 0, 0);
    transpose_cvt<<<dim3(18, 32, 128), 256, 0, stream>>>(
        x, xt, 1024, 576, (size_t)1024 * 576, (size_t)576 * 1024);
    pool_kernel<<<dim3(B_ * QN), 256, 0, stream>>>(xt, xp);
    gemm_nt<0><<<dim3(576, 8), 256, 0, stream>>>(xt, Wkt, kbuf, nullptr);
    gemm_nt<1><<<dim3(8, 576), 256, 0, stream>>>(Wvt, xt, vtb, nullptr);
    gemm_nt<0><<<dim3(144, 8), 256, 0, stream>>>(xp, Wqt, qbuf, nullptr);
    attn_kernel<<<dim3(B_ * NH * 3), 192, 0, stream>>>(qbuf, kbuf, vtb, rph, rpw, attno);
    gemm_nt<2><<<dim3(8, 144), 256, 0, stream>>>(Wpt, attno, d_out, bp);
}

// Round 3
// 1193.550 us; speedup vs baseline: 1.3085x; 1.3085x over previous
//
#include <hip/hip_runtime.h>
#include <hip/hip_bf16.h>

using bf16 = __hip_bfloat16;
typedef __attribute__((ext_vector_type(8))) short short8;
typedef __attribute__((ext_vector_type(4))) float f32x4;

#define MFMA(a,b,c) __builtin_amdgcn_mfma_f32_16x16x32_bf16(a, b, c, 0, 0, 0)

#define B_      128
#define C_      1024
#define NH      8
#define HD      128
#define HW      24
#define NTOK    576
#define QH      12
#define QN      144

static __device__ __forceinline__ float bf2f(bf16 v) { return __bfloat162float(v); }
static __device__ __forceinline__ bf16  f2bf(float v) { return __float2bfloat16(v); }
static __device__ __forceinline__ float s2f(short s) {
    return __uint_as_float(((unsigned)(unsigned short)s) << 16);
}

__device__ __forceinline__ void gll16(const bf16* src, bf16* dst_lds) {
    __builtin_amdgcn_global_load_lds(
        (__attribute__((address_space(1))) const unsigned int*)src,
        (__attribute__((address_space(3))) unsigned int*)dst_lds,
        16, 0, 0);
}

// ---------------- transpose + fp32->bf16 convert: out[c][r] = in[r][c] ----------------
__global__ __launch_bounds__(256) void transpose_cvt(
    const float* __restrict__ in, bf16* __restrict__ out,
    int R, int Ccols, size_t ibs, size_t obs)
{
    __shared__ float tile[32][33];
    const float* ib = in + (size_t)blockIdx.z * ibs;
    bf16* ob = out + (size_t)blockIdx.z * obs;
    int c0 = blockIdx.x * 32, r0 = blockIdx.y * 32;
    int tx = threadIdx.x & 31, ty = threadIdx.x >> 5;
    #pragma unroll
    for (int i = 0; i < 32; i += 8)
        tile[ty + i][tx] = ib[(size_t)(r0 + ty + i) * Ccols + c0 + tx];
    __syncthreads();
    #pragma unroll
    for (int i = 0; i < 32; i += 8)
        ob[(size_t)(c0 + ty + i) * R + r0 + tx] = f2bf(tile[tx][ty + i]);
}

// ---------------- 3x3 s2 avg pool (count_include_pad), xt[B*N][C] -> xp[B*qN][C] ------
__global__ __launch_bounds__(256) void pool_kernel(const bf16* __restrict__ xt,
                                                   bf16* __restrict__ xp)
{
    int bqn = blockIdx.x;
    int b = bqn / QN, qn = bqn % QN;
    int y = qn / QH, x = qn % QH;
    int t = threadIdx.x;
    float s0 = 0, s1 = 0, s2 = 0, s3 = 0;
    for (int dy = 0; dy < 3; dy++) {
        int hy = 2 * y - 1 + dy;
        if (hy < 0 || hy >= HW) continue;
        for (int dx = 0; dx < 3; dx++) {
            int hx = 2 * x - 1 + dx;
            if (hx < 0 || hx >= HW) continue;
            const bf16* row = xt + (size_t)(b * NTOK + hy * HW + hx) * C_;
            s0 += bf2f(row[t]);
            s1 += bf2f(row[t + 256]);
            s2 += bf2f(row[t + 512]);
            s3 += bf2f(row[t + 768]);
        }
    }
    bf16* o = xp + (size_t)bqn * C_;
    const float n = 1.f / 9.f;
    o[t] = f2bf(s0 * n); o[t + 256] = f2bf(s1 * n);
    o[t + 512] = f2bf(s2 * n); o[t + 768] = f2bf(s3 * n);
}

// ---------------- NT GEMM: C[m][n] = sum_k A[m][k]*Bt[n][k], K=1024 -------------------
// EPI 0: bf16 row-major [M][1024]
// EPI 2: fp32 out + bias: row=channel, col=token -> out[b*147456 + ch*144 + qn]
// EPI 3: K frag-ready: row=token(b*576+n), col=channel
// EPI 4: V frag-ready: row=channel, col=token(b*576+n)
template<int EPI>
__global__ __launch_bounds__(256, 2) void gemm_nt(
    const bf16* __restrict__ A, const bf16* __restrict__ Bt,
    void* __restrict__ Cout, const float* __restrict__ bias)
{
    __shared__ bf16 lds[2][2][128 * 64];
    const int tid = threadIdx.x;
    const int wv = tid >> 6, ln = tid & 63;
    const int m0 = blockIdx.x * 128, n0 = blockIdx.y * 128;
    const int wr = wv >> 1, wc = wv & 1;
    const int l15 = ln & 15, l4 = ln >> 4;
    const int r8 = ln >> 3, sl = ln & 7;
    const int sg = sl ^ r8;

    const bf16* gA = A + (size_t)m0 * C_;
    const bf16* gB = Bt + (size_t)n0 * C_;

    f32x4 zero = {0.f, 0.f, 0.f, 0.f};
    f32x4 acc[4][4];
    #pragma unroll
    for (int i = 0; i < 4; i++)
        #pragma unroll
        for (int j = 0; j < 4; j++) acc[i][j] = zero;

    auto stage = [&](int kt, int d) {
        const bf16* sa = gA + kt * 64;
        const bf16* sb = gB + kt * 64;
        bf16* la = lds[d][0];
        bf16* lb = lds[d][1];
        #pragma unroll
        for (int i = 0; i < 4; i++) {
            int chunk = wv * 4 + i;
            gll16(sa + (size_t)(chunk * 8 + r8) * C_ + sg * 8, la + chunk * 512);
            gll16(sb + (size_t)(chunk * 8 + r8) * C_ + sg * 8, lb + chunk * 512);
        }
    };

    stage(0, 0);
    asm volatile("s_waitcnt vmcnt(0)");
    __syncthreads();

    int cur = 0;
    for (int kt = 0; kt < 16; kt++) {
        if (kt < 15) stage(kt + 1, cur ^ 1);
        const bf16* la = lds[cur][0];
        const bf16* lb = lds[cur][1];
        #pragma unroll
        for (int ks = 0; ks < 2; ks++) {
            short8 af[4], bfr[4];
            #pragma unroll
            for (int fm = 0; fm < 4; fm++) {
                int row = wr * 64 + fm * 16 + l15;
                int slot = (ks * 4 + l4) ^ (row & 7);
                af[fm] = *(const short8*)((const char*)la + row * 128 + slot * 16);
            }
            #pragma unroll
            for (int fn = 0; fn < 4; fn++) {
                int row = wc * 64 + fn * 16 + l15;
                int slot = (ks * 4 + l4) ^ (row & 7);
                bfr[fn] = *(const short8*)((const char*)lb + row * 128 + slot * 16);
            }
            #pragma unroll
            for (int fm = 0; fm < 4; fm++)
                #pragma unroll
                for (int fn = 0; fn < 4; fn++)
                    acc[fm][fn] = MFMA(af[fm], bfr[fn], acc[fm][fn]);
        }
        asm volatile("s_waitcnt vmcnt(0)");
        __syncthreads();
        cur ^= 1;
    }

    #pragma unroll
    for (int fm = 0; fm < 4; fm++) {
        #pragma unroll
        for (int fn = 0; fn < 4; fn++) {
            #pragma unroll
            for (int r = 0; r < 4; r++) {
                int row = m0 + wr * 64 + fm * 16 + l4 * 4 + r;
                int col = n0 + wc * 64 + fn * 16 + l15;
                float v = acc[fm][fn][r];
                if constexpr (EPI == 0) {
                    ((bf16*)Cout)[(size_t)row * C_ + col] = f2bf(v);
                } else if constexpr (EPI == 2) {
                    int bb = col / QN, qn = col % QN;
                    ((float*)Cout)[(size_t)bb * (C_ * QN) + (size_t)row * QN + qn] =
                        v + bias[row];
                } else if constexpr (EPI == 3) {
                    // K frag-ready: row = global token, col = channel
                    int b = row / NTOK, n = row % NTOK;
                    int h = col >> 7, ci = col & 127;
                    int ks2 = ci >> 5, chunk = (ci >> 3) & 3, e = ci & 7;
                    int kt2 = n >> 6, kf = (n >> 4) & 3, klane = n & 15;
                    int lane = chunk * 16 + klane;
                    size_t addr = ((((size_t)(b * NH + h) * 9 + kt2) * 4 + kf) * 4 + ks2) * 512
                                  + lane * 8 + e;
                    ((bf16*)Cout)[addr] = f2bf(v);
                } else {
                    // V frag-ready: row = channel, col = global token
                    int b = col / NTOK, n = col % NTOK;
                    int h = row >> 7, ci = row & 127;
                    int hf = ci >> 4, lanelo = ci & 15;
                    int kt2 = n >> 6, ks2 = (n >> 5) & 1, chunk = (n >> 3) & 3, e = n & 7;
                    int lane = chunk * 16 + lanelo;
                    size_t addr = ((((size_t)(b * NH + h) * 9 + kt2) * 8 + hf) * 2 + ks2) * 512
                                  + lane * 8 + e;
                    ((bf16*)Cout)[addr] = f2bf(v);
                }
            }
        }
    }
}

// ---------------- fused pooled-Q attention ---------------------------------------------
// grid: B*NH blocks; block = all 144 q-rows of one (b,h); 9 waves x 16 q-rows.
// K/V staged through LDS from fragment-ready global layouts (coalesced), double-buffered.
__global__ __launch_bounds__(576, 1) void attn_kernel(
    const bf16* __restrict__ qbuf, const bf16* __restrict__ kfr,
    const bf16* __restrict__ vfr, const float* __restrict__ rph,
    const float* __restrict__ rpw, bf16* __restrict__ attno)
{
    __shared__ float relh[QN * 24];       // 13.8 KB
    __shared__ float relw[QN * 24];       // 13.8 KB
    __shared__ bf16  kbufL[2][8192];      // 32 KB
    __shared__ bf16  vbufL[2][8192];      // 32 KB
    __shared__ char  plds[9][2048];       // 18 KB

    const int bh = blockIdx.x;
    const int b = bh >> 3, h = bh & 7;
    const int w = threadIdx.x >> 6, ln = threadIdx.x & 63;
    const int l15 = ln & 15, l4 = ln >> 4;

    const bf16* qbase = qbuf + ((size_t)(b * QN + w * 16) * C_ + h * HD);
    const bf16* kh = kfr + (size_t)(b * NH + h) * 9 * 8192;
    const bf16* vh = vfr + (size_t)(b * NH + h) * 9 * 8192;

    // ---- relative-position bias tables: one (q-row, kk-group) per thread ----
    {
        int t = threadIdx.x;
        int qr = t >> 2, kkg = t & 3;
        int y = qr / 12, x = qr - y * 12;
        const short8* qrow = (const short8*)(qbuf + ((size_t)(b * QN + qr) * C_ + h * HD));
        float sh[6] = {0, 0, 0, 0, 0, 0}, sw[6] = {0, 0, 0, 0, 0, 0};
        for (int c0 = 0; c0 < 16; c0++) {
            short8 qv = qrow[c0];
            float qf[8];
            #pragma unroll
            for (int j = 0; j < 8; j++) qf[j] = s2f(qv[j]);
            #pragma unroll
            for (int j = 0; j < 6; j++) {
                int kk = j * 4 + kkg;
                const f32x4* rh = (const f32x4*)(rph + (size_t)(2 * y - kk + 23) * HD + c0 * 8);
                const f32x4* rw = (const f32x4*)(rpw + (size_t)(2 * x - kk + 23) * HD + c0 * 8);
                f32x4 h0 = rh[0], h1 = rh[1], w0 = rw[0], w1 = rw[1];
                #pragma unroll
                for (int u = 0; u < 4; u++) {
                    sh[j] = fmaf(qf[u], h0[u], sh[j]);
                    sw[j] = fmaf(qf[u], w0[u], sw[j]);
                    sh[j] = fmaf(qf[u + 4], h1[u], sh[j]);
                    sw[j] = fmaf(qf[u + 4], w1[u], sw[j]);
                }
            }
        }
        #pragma unroll
        for (int j = 0; j < 6; j++) {
            relh[qr * 24 + j * 4 + kkg] = sh[j];
            relw[qr * 24 + j * 4 + kkg] = sw[j];
        }
    }

    // ---- persistent q fragments (A-operand layout), 16 rows per wave ----
    short8 qfr[4];
    #pragma unroll
    for (int ks = 0; ks < 4; ks++)
        qfr[ks] = *(const short8*)(qbase + (size_t)l15 * C_ + ks * 32 + l4 * 8);

    f32x4 zero = {0.f, 0.f, 0.f, 0.f};
    f32x4 Of[8];
    float mrun[4], lrun[4];
    #pragma unroll
    for (int hf = 0; hf < 8; hf++) Of[hf] = zero;
    #pragma unroll
    for (int r = 0; r < 4; r++) { mrun[r] = -1e30f; lrun[r] = 0.f; }

    const float scale = 0.08838834764831845f;  // 1/sqrt(128)
    const int rbase = (w * 16 + l4 * 4) * 24;

    // ---- K/V tile staging (coalesced, frag-stream order, linear LDS) ----
    auto stage = [&](int kt, int d) {
        if (w < 8) {
            const bf16* kb = kh + (size_t)kt * 8192;
            const bf16* vb = vh + (size_t)kt * 8192;
            #pragma unroll
            for (int i = 0; i < 4; i++) {
                int s = w * 4 + i;
                if (s < 16) gll16(kb + s * 512 + ln * 8, &kbufL[d][s * 512]);
                else        gll16(vb + (s - 16) * 512 + ln * 8, &vbufL[d][(s - 16) * 512]);
            }
        }
    };

    stage(0, 0);
    __syncthreads();   // drains vmcnt+lgkmcnt (rel tables also ready)

    int cur = 0;
    for (int kt = 0; kt < 9; kt++) {
        if (kt < 8) stage(kt + 1, cur ^ 1);
        // S = q @ k^T  (16 x 64 per wave)
        f32x4 S[4];
        #pragma unroll
        for (int kf = 0; kf < 4; kf++) {
            short8 bfr[4];
            #pragma unroll
            for (int ks = 0; ks < 4; ks++)
                bfr[ks] = *(const short8*)(&kbufL[cur][(kf * 4 + ks) * 512 + ln * 8]);
            f32x4 acc = zero;
            #pragma unroll
            for (int ks = 0; ks < 4; ks++) acc = MFMA(qfr[ks], bfr[ks], acc);
            S[kf] = acc;
        }
        // scale + rel-pos bias
        #pragma unroll
        for (int kf = 0; kf < 4; kf++) {
            int key = kt * 64 + kf * 16 + l15;
            int kr = key / 24, kc = key - kr * 24;
            #pragma unroll
            for (int r = 0; r < 4; r++)
                S[kf][r] = S[kf][r] * scale + relh[rbase + r * 24 + kr] +
                           relw[rbase + r * 24 + kc];
        }
        // online softmax (rows live in 16-lane groups)
        float alpha[4];
        #pragma unroll
        for (int r = 0; r < 4; r++) {
            float mt = fmaxf(fmaxf(S[0][r], S[1][r]), fmaxf(S[2][r], S[3][r]));
            #pragma unroll
            for (int d = 1; d < 16; d <<= 1) mt = fmaxf(mt, __shfl_xor(mt, d, 64));
            float mn = fmaxf(mrun[r], mt);
            alpha[r] = __expf(mrun[r] - mn);
            mrun[r] = mn;
            float ps = 0.f;
            #pragma unroll
            for (int kf = 0; kf < 4; kf++) {
                float p = __expf(S[kf][r] - mn);
                S[kf][r] = p;
                ps += p;
            }
            #pragma unroll
            for (int d = 1; d < 16; d <<= 1) ps += __shfl_xor(ps, d, 64);
            lrun[r] = lrun[r] * alpha[r] + ps;
        }
        // rescale O
        #pragma unroll
        for (int hf = 0; hf < 8; hf++)
            #pragma unroll
            for (int r = 0; r < 4; r++) Of[hf][r] *= alpha[r];
        // P -> LDS (bf16, XOR-swizzled 128B rows), per-wave buffer
        #pragma unroll
        for (int kf = 0; kf < 4; kf++) {
            int key = kf * 16 + l15;
            int slotb = key >> 3, kin = key & 7;
            #pragma unroll
            for (int r = 0; r < 4; r++) {
                int row = l4 * 4 + r;
                int byt = row * 128 + ((slotb ^ (row & 7)) << 4) + kin * 2;
                *(bf16*)(&plds[w][byt]) = f2bf(S[kf][r]);
            }
        }
        // PV: O += P @ V
        #pragma unroll
        for (int ks2 = 0; ks2 < 2; ks2++) {
            int slot = (ks2 * 4 + l4) ^ (l15 & 7);
            short8 pa = *(const short8*)(&plds[w][l15 * 128 + slot * 16]);
            #pragma unroll
            for (int hf = 0; hf < 8; hf++) {
                short8 vb = *(const short8*)(&vbufL[cur][(hf * 2 + ks2) * 512 + ln * 8]);
                Of[hf] = MFMA(pa, vb, Of[hf]);
            }
        }
        __syncthreads();
        cur ^= 1;
    }

    // epilogue: O/l + q residual
    bf16* obase = attno + ((size_t)(b * QN + w * 16) * C_ + h * HD);
    #pragma unroll
    for (int r = 0; r < 4; r++) {
        int qr = l4 * 4 + r;
        float inv = 1.f / lrun[r];
        #pragma unroll
        for (int hf = 0; hf < 8; hf++) {
            int hd = hf * 16 + l15;
            float o = Of[hf][r] * inv + bf2f(qbase[(size_t)qr * C_ + hd]);
            obase[(size_t)qr * C_ + hd] = f2bf(o);
        }
    }
}

extern "C" void kernel_launch(void* const* d_in, const int* in_sizes, int n_in,
                              void* d_out, int out_size, void* d_ws, size_t ws_size,
                              hipStream_t stream)
{
    const float* x   = (const float*)d_in[0];
    const float* Wq  = (const float*)d_in[1];
    const float* Wk  = (const float*)d_in[2];
    const float* Wv  = (const float*)d_in[3];
    const float* Wp  = (const float*)d_in[4];
    const float* bp  = (const float*)d_in[5];
    const float* rph = (const float*)d_in[6];
    const float* rpw = (const float*)d_in[7];

    char* ws = (char*)d_ws;
    const size_t MB = 1024 * 1024;
    bf16* Wqt  = (bf16*)(ws + 0 * MB);
    bf16* Wkt  = (bf16*)(ws + 2 * MB);
    bf16* Wvt  = (bf16*)(ws + 4 * MB);
    bf16* Wpt  = (bf16*)(ws + 6 * MB);
    bf16* xt   = (bf16*)(ws + 8 * MB);          // 144 MB, reused as attno
    bf16* kfrb = (bf16*)(ws + 152 * MB);        // 144 MB (frag-ready K)
    bf16* vfrb = (bf16*)(ws + 296 * MB);        // 144 MB (frag-ready V)
    bf16* xp   = (bf16*)(ws + 440 * MB);        // 36 MB
    bf16* qbuf = (bf16*)(ws + 476 * MB);        // 36 MB -> end 512 MB
    bf16* attno = xt;

    transpose_cvt<<<dim3(32, 32, 1), 256, 0, stream>>>(Wq, Wqt, 1024, 1024, 0, 0);
    transpose_cvt<<<dim3(32, 32, 1), 256, 0, stream>>>(Wk, Wkt, 1024, 1024, 0, 0);
    transpose_cvt<<<dim3(32, 32, 1), 256, 0, stream>>>(Wv, Wvt, 1024, 1024, 0, 0);
    transpose_cvt<<<dim3(32, 32, 1), 256, 0, stream>>>(Wp, Wpt, 1024, 1024, 0, 0);
    transpose_cvt<<<dim3(18, 32, 128), 256, 0, stream>>>(
        x, xt, 1024, 576, (size_t)1024 * 576, (size_t)576 * 1024);
    pool_kernel<<<dim3(B_ * QN), 256, 0, stream>>>(xt, xp);
    gemm_nt<3><<<dim3(576, 8), 256, 0, stream>>>(xt, Wkt, kfrb, nullptr);
    gemm_nt<4><<<dim3(8, 576), 256, 0, stream>>>(Wvt, xt, vfrb, nullptr);
    gemm_nt<0><<<dim3(144, 8), 256, 0, stream>>>(xp, Wqt, qbuf, nullptr);
    attn_kernel<<<dim3(B_ * NH), 576, 0, stream>>>(qbuf, kfrb, vfrb, rph, rpw, attno);
    gemm_nt<2><<<dim3(8, 144), 256, 0, stream>>>(Wpt, attno, d_out, bp);
}

// Round 5
// 1184.314 us; speedup vs baseline: 1.3187x; 1.0078x over previous
//
#include <hip/hip_runtime.h>
#include <hip/hip_bf16.h>

using bf16 = __hip_bfloat16;
typedef __attribute__((ext_vector_type(8))) short short8;
typedef __attribute__((ext_vector_type(4))) short s16x4;
typedef __attribute__((ext_vector_type(4))) float f32x4;

#define MFMA(a,b,c) __builtin_amdgcn_mfma_f32_16x16x32_bf16(a, b, c, 0, 0, 0)

#define B_      128
#define C_      1024
#define NH      8
#define HD      128
#define HW      24
#define NTOK    576
#define QH      12
#define QN      144

static __device__ __forceinline__ float bf2f(bf16 v) { return __bfloat162float(v); }
static __device__ __forceinline__ bf16  f2bf(float v) { return __float2bfloat16(v); }
static __device__ __forceinline__ float s2f(short s) {
    return __uint_as_float(((unsigned)(unsigned short)s) << 16);
}
static __device__ __forceinline__ unsigned bfbits(float v) {
    bf16 t = f2bf(v);
    return (unsigned)*(unsigned short*)&t;
}

__device__ __forceinline__ void gll16(const bf16* src, bf16* dst_lds) {
    __builtin_amdgcn_global_load_lds(
        (__attribute__((address_space(1))) const unsigned int*)src,
        (__attribute__((address_space(3))) unsigned int*)dst_lds,
        16, 0, 0);
}

// ---------------- transpose + fp32->bf16 convert: out[c][r] = in[r][c] ----------------
__global__ __launch_bounds__(256) void transpose_cvt(
    const float* __restrict__ in, bf16* __restrict__ out,
    int R, int Ccols, size_t ibs, size_t obs)
{
    __shared__ float tile[32][33];
    const float* ib = in + (size_t)blockIdx.z * ibs;
    bf16* ob = out + (size_t)blockIdx.z * obs;
    int c0 = blockIdx.x * 32, r0 = blockIdx.y * 32;
    int tx = threadIdx.x & 31, ty = threadIdx.x >> 5;
    #pragma unroll
    for (int i = 0; i < 32; i += 8)
        tile[ty + i][tx] = ib[(size_t)(r0 + ty + i) * Ccols + c0 + tx];
    __syncthreads();
    #pragma unroll
    for (int i = 0; i < 32; i += 8)
        ob[(size_t)(c0 + ty + i) * R + r0 + tx] = f2bf(tile[tx][ty + i]);
}

// ---------------- 3x3 s2 avg pool (count_include_pad), xt[B*N][C] -> xp[B*qN][C] ------
__global__ __launch_bounds__(256) void pool_kernel(const bf16* __restrict__ xt,
                                                   bf16* __restrict__ xp)
{
    int bqn = blockIdx.x;
    int b = bqn / QN, qn = bqn % QN;
    int y = qn / QH, x = qn % QH;
    int t = threadIdx.x;
    float s0 = 0, s1 = 0, s2 = 0, s3 = 0;
    for (int dy = 0; dy < 3; dy++) {
        int hy = 2 * y - 1 + dy;
        if (hy < 0 || hy >= HW) continue;
        for (int dx = 0; dx < 3; dx++) {
            int hx = 2 * x - 1 + dx;
            if (hx < 0 || hx >= HW) continue;
            const bf16* row = xt + (size_t)(b * NTOK + hy * HW + hx) * C_;
            s0 += bf2f(row[t]);
            s1 += bf2f(row[t + 256]);
            s2 += bf2f(row[t + 512]);
            s3 += bf2f(row[t + 768]);
        }
    }
    bf16* o = xp + (size_t)bqn * C_;
    const float n = 1.f / 9.f;
    o[t] = f2bf(s0 * n); o[t + 256] = f2bf(s1 * n);
    o[t + 512] = f2bf(s2 * n); o[t + 768] = f2bf(s3 * n);
}

// ---------------- NT GEMM: C[m][n] = sum_k A[m][k]*Bt[n][k], K=1024 -------------------
// EPI 0: bf16 row-major [M][1024]
// EPI 2: fp32 out + bias: row=channel, col=token -> out[b*147456 + ch*144 + qn]
// EPI 3: K frag-ready (32-key tiles): row=token(b*576+n), col=channel
// EPI 4: V frag-ready (32-key tiles): row=channel, col=token(b*576+n)
template<int EPI>
__global__ __launch_bounds__(256, 2) void gemm_nt(
    const bf16* __restrict__ A, const bf16* __restrict__ Bt,
    void* __restrict__ Cout, const float* __restrict__ bias)
{
    __shared__ bf16 lds[2][2][128 * 64];
    const int tid = threadIdx.x;
    const int wv = tid >> 6, ln = tid & 63;
    const int m0 = blockIdx.x * 128, n0 = blockIdx.y * 128;
    const int wr = wv >> 1, wc = wv & 1;
    const int l15 = ln & 15, l4 = ln >> 4;
    const int r8 = ln >> 3, sl = ln & 7;
    const int sg = sl ^ r8;

    const bf16* gA = A + (size_t)m0 * C_;
    const bf16* gB = Bt + (size_t)n0 * C_;

    f32x4 zero = {0.f, 0.f, 0.f, 0.f};
    f32x4 acc[4][4];
    #pragma unroll
    for (int i = 0; i < 4; i++)
        #pragma unroll
        for (int j = 0; j < 4; j++) acc[i][j] = zero;

    auto stage = [&](int kt, int d) {
        const bf16* sa = gA + kt * 64;
        const bf16* sb = gB + kt * 64;
        bf16* la = lds[d][0];
        bf16* lb = lds[d][1];
        #pragma unroll
        for (int i = 0; i < 4; i++) {
            int chunk = wv * 4 + i;
            gll16(sa + (size_t)(chunk * 8 + r8) * C_ + sg * 8, la + chunk * 512);
            gll16(sb + (size_t)(chunk * 8 + r8) * C_ + sg * 8, lb + chunk * 512);
        }
    };

    stage(0, 0);
    asm volatile("s_waitcnt vmcnt(0)");
    __syncthreads();

    int cur = 0;
    for (int kt = 0; kt < 16; kt++) {
        if (kt < 15) stage(kt + 1, cur ^ 1);
        const bf16* la = lds[cur][0];
        const bf16* lb = lds[cur][1];
        #pragma unroll
        for (int ks = 0; ks < 2; ks++) {
            short8 af[4], bfr[4];
            #pragma unroll
            for (int fm = 0; fm < 4; fm++) {
                int row = wr * 64 + fm * 16 + l15;
                int slot = (ks * 4 + l4) ^ (row & 7);
                af[fm] = *(const short8*)((const char*)la + row * 128 + slot * 16);
            }
            #pragma unroll
            for (int fn = 0; fn < 4; fn++) {
                int row = wc * 64 + fn * 16 + l15;
                int slot = (ks * 4 + l4) ^ (row & 7);
                bfr[fn] = *(const short8*)((const char*)lb + row * 128 + slot * 16);
            }
            #pragma unroll
            for (int fm = 0; fm < 4; fm++)
                #pragma unroll
                for (int fn = 0; fn < 4; fn++)
                    acc[fm][fn] = MFMA(af[fm], bfr[fn], acc[fm][fn]);
        }
        asm volatile("s_waitcnt vmcnt(0)");
        __syncthreads();
        cur ^= 1;
    }

    #pragma unroll
    for (int fm = 0; fm < 4; fm++) {
        #pragma unroll
        for (int fn = 0; fn < 4; fn++) {
            #pragma unroll
            for (int r = 0; r < 4; r++) {
                int row = m0 + wr * 64 + fm * 16 + l4 * 4 + r;
                int col = n0 + wc * 64 + fn * 16 + l15;
                float v = acc[fm][fn][r];
                if constexpr (EPI == 0) {
                    ((bf16*)Cout)[(size_t)row * C_ + col] = f2bf(v);
                } else if constexpr (EPI == 2) {
                    int bb = col / QN, qn = col % QN;
                    ((float*)Cout)[(size_t)bb * (C_ * QN) + (size_t)row * QN + qn] =
                        v + bias[row];
                } else if constexpr (EPI == 3) {
                    // K frag-ready: row = global token, col = channel
                    int b = row / NTOK, n = row % NTOK;
                    int h = col >> 7, ci = col & 127;
                    int kt2 = n >> 5, kf = (n >> 4) & 1, klane = n & 15;
                    int ks2 = ci >> 5, chunk = (ci >> 3) & 3, e = ci & 7;
                    int lane = chunk * 16 + klane;
                    size_t addr = ((((size_t)(b * NH + h) * 18 + kt2) * 2 + kf) * 4 + ks2) * 512
                                  + lane * 8 + e;
                    ((bf16*)Cout)[addr] = f2bf(v);
                } else {
                    // V frag-ready: row = channel, col = global token
                    int b = col / NTOK, n = col % NTOK;
                    int h = row >> 7, ci = row & 127;
                    int hf = (ci >> 4) & 7, lanelo = ci & 15;
                    int kt2 = n >> 5, chunk = (n >> 3) & 3, e = n & 7;
                    int lane = chunk * 16 + lanelo;
                    size_t addr = (((size_t)(b * NH + h) * 18 + kt2) * 8 + hf) * 512
                                  + lane * 8 + e;
                    ((bf16*)Cout)[addr] = f2bf(v);
                }
            }
        }
    }
}

// ---------------- fused pooled-Q attention ---------------------------------------------
// grid: B*NH blocks; block = all 144 q-rows of one (b,h); 9 waves x 16 q-rows.
// Swapped QK^T (lane owns P-row) and swapped PV; 32-key tiles, 2 blocks/CU.
__global__ __launch_bounds__(576) void attn_kernel(
    const bf16* __restrict__ qbuf, const bf16* __restrict__ kfr,
    const bf16* __restrict__ vfr, const float* __restrict__ rph,
    const float* __restrict__ rpw, bf16* __restrict__ attno)
{
    __shared__ float relh[QN * 24];       // 13.5 KB
    __shared__ float relw[QN * 24];       // 13.5 KB
    __shared__ bf16  kbufL[2][4096];      // 16 KB
    __shared__ bf16  vbufL[2][4096];      // 16 KB
    __shared__ char  plds[9][1024];       // 9 KB   -> 68 KB total, 2 blocks/CU

    const int bh = blockIdx.x;
    const int b = bh >> 3, h = bh & 7;
    const int w = threadIdx.x >> 6, ln = threadIdx.x & 63;
    const int l15 = ln & 15, l4 = ln >> 4;

    const bf16* qbase = qbuf + ((size_t)(b * QN + w * 16) * C_ + h * HD);
    const bf16* kh = kfr + (size_t)(b * NH + h) * 18 * 4096;
    const bf16* vh = vfr + (size_t)(b * NH + h) * 18 * 4096;

    // ---- relative-position bias tables: one (q-row, kk-group) per thread ----
    {
        int t = threadIdx.x;
        int qr = t >> 2, kkg = t & 3;
        int y = qr / 12, x = qr - y * 12;
        const short8* qrow = (const short8*)(qbuf + ((size_t)(b * QN + qr) * C_ + h * HD));
        float sh[6] = {0, 0, 0, 0, 0, 0}, sw[6] = {0, 0, 0, 0, 0, 0};
        for (int c0 = 0; c0 < 16; c0++) {
            short8 qv = qrow[c0];
            float qf[8];
            #pragma unroll
            for (int j = 0; j < 8; j++) qf[j] = s2f(qv[j]);
            #pragma unroll
            for (int j = 0; j < 6; j++) {
                int kk = j * 4 + kkg;
                const f32x4* rh = (const f32x4*)(rph + (size_t)(2 * y - kk + 23) * HD + c0 * 8);
                const f32x4* rw = (const f32x4*)(rpw + (size_t)(2 * x - kk + 23) * HD + c0 * 8);
                f32x4 h0 = rh[0], h1 = rh[1], w0 = rw[0], w1 = rw[1];
                #pragma unroll
                for (int u = 0; u < 4; u++) {
                    sh[j] = fmaf(qf[u], h0[u], sh[j]);
                    sw[j] = fmaf(qf[u], w0[u], sw[j]);
                    sh[j] = fmaf(qf[u + 4], h1[u], sh[j]);
                    sw[j] = fmaf(qf[u + 4], w1[u], sw[j]);
                }
            }
        }
        #pragma unroll
        for (int j = 0; j < 6; j++) {
            relh[qr * 24 + j * 4 + kkg] = sh[j];
            relw[qr * 24 + j * 4 + kkg] = sw[j];
        }
    }

    // ---- persistent q fragments (B-operand: row=q=l15, k=ks*32+l4*8+e) ----
    short8 qfr[4];
    #pragma unroll
    for (int ks = 0; ks < 4; ks++)
        qfr[ks] = *(const short8*)(qbase + (size_t)l15 * C_ + ks * 32 + l4 * 8);

    f32x4 zero = {0.f, 0.f, 0.f, 0.f};
    f32x4 Of[8];
    #pragma unroll
    for (int hf = 0; hf < 8; hf++) Of[hf] = zero;
    float mrun = -1e30f, lrun = 0.f;

    const float scale = 0.08838834764831845f;  // 1/sqrt(128)
    const int rbase = (w * 16 + l15) * 24;     // this lane's q row in rel tables

    auto stage = [&](int kt, int d) {
        if (w < 8) {
            #pragma unroll
            for (int i = 0; i < 2; i++) {
                int s = w * 2 + i;
                if (s < 8) gll16(kh + (size_t)kt * 4096 + s * 512 + ln * 8,
                                 &kbufL[d][s * 512]);
                else       gll16(vh + (size_t)kt * 4096 + (s - 8) * 512 + ln * 8,
                                 &vbufL[d][(s - 8) * 512]);
            }
        }
    };

    stage(0, 0);
    __syncthreads();

    int cur = 0;
    for (int kt = 0; kt < 18; kt++) {
        if (kt < 17) stage(kt + 1, cur ^ 1);
        // S = K @ q^T (swapped): lane holds S[key=kf*16+l4*4+r][q=l15]
        f32x4 S[2];
        #pragma unroll
        for (int kf = 0; kf < 2; kf++) {
            f32x4 acc = zero;
            #pragma unroll
            for (int ks = 0; ks < 4; ks++) {
                short8 kb = *(const short8*)(&kbufL[cur][(kf * 4 + ks) * 512 + ln * 8]);
                acc = MFMA(kb, qfr[ks], acc);
            }
            S[kf] = acc;
        }
        // scale + rel-pos bias (per-lane keys)
        #pragma unroll
        for (int kf = 0; kf < 2; kf++) {
            #pragma unroll
            for (int r = 0; r < 4; r++) {
                int key = kt * 32 + kf * 16 + l4 * 4 + r;
                int kr = key / 24, kc = key - kr * 24;
                S[kf][r] = S[kf][r] * scale + relh[rbase + kr] + relw[rbase + kc];
            }
        }
        // in-lane softmax (row = this lane's q; 8 keys/lane, x4 lanes)
        float pm = fmaxf(fmaxf(fmaxf(S[0][0], S[0][1]), fmaxf(S[0][2], S[0][3])),
                         fmaxf(fmaxf(S[1][0], S[1][1]), fmaxf(S[1][2], S[1][3])));
        pm = fmaxf(pm, __shfl_xor(pm, 16, 64));
        pm = fmaxf(pm, __shfl_xor(pm, 32, 64));
        if (!__all(pm <= mrun + 8.f)) {       // defer-max (T13)
            float mn = fmaxf(mrun, pm);
            float alpha = __expf(mrun - mn);
            #pragma unroll
            for (int hf = 0; hf < 8; hf++)
                #pragma unroll
                for (int r = 0; r < 4; r++) Of[hf][r] *= alpha;
            lrun *= alpha;
            mrun = mn;
        }
        float ps = 0.f;
        #pragma unroll
        for (int kf = 0; kf < 2; kf++)
            #pragma unroll
            for (int r = 0; r < 4; r++) {
                float p = __expf(S[kf][r] - mrun);
                S[kf][r] = p;
                ps += p;
            }
        ps += __shfl_xor(ps, 16, 64);
        ps += __shfl_xor(ps, 32, 64);
        lrun += ps;
        // pack P -> LDS (row=q=l15, 32 keys x bf16 = 64B/row), b64 writes
        #pragma unroll
        for (int kf = 0; kf < 2; kf++) {
            unsigned u0 = bfbits(S[kf][0]) | (bfbits(S[kf][1]) << 16);
            unsigned u1 = bfbits(S[kf][2]) | (bfbits(S[kf][3]) << 16);
            *(unsigned long long*)(&plds[w][l15 * 64 + kf * 32 + l4 * 8]) =
                ((unsigned long long)u1 << 32) | u0;
        }
        // P B-frag: row=q=l15, key=l4*8+e
        short8 pf = *(const short8*)(&plds[w][l15 * 64 + l4 * 16]);
        // PV swapped: Of[hd][q]
        #pragma unroll
        for (int hf = 0; hf < 8; hf++) {
            short8 vb = *(const short8*)(&vbufL[cur][hf * 512 + ln * 8]);
            Of[hf] = MFMA(vb, pf, Of[hf]);
        }
        __syncthreads();
        cur ^= 1;
    }

    // epilogue: O/l + q residual; lane stores row q=l15, hd = hf*16 + l4*4 + r
    bf16* obase = attno + ((size_t)(b * QN + w * 16) * C_ + h * HD);
    float inv = 1.f / lrun;
    #pragma unroll
    for (int hf = 0; hf < 8; hf++) {
        s16x4 qres = *(const s16x4*)(qbase + (size_t)l15 * C_ + hf * 16 + l4 * 4);
        s16x4 o;
        #pragma unroll
        for (int r = 0; r < 4; r++) {
            float v = Of[hf][r] * inv + s2f(qres[r]);
            o[r] = (short)bfbits(v);
        }
        *(s16x4*)(obase + (size_t)l15 * C_ + hf * 16 + l4 * 4) = o;
    }
}

extern "C" void kernel_launch(void* const* d_in, const int* in_sizes, int n_in,
                              void* d_out, int out_size, void* d_ws, size_t ws_size,
                              hipStream_t stream)
{
    const float* x   = (const float*)d_in[0];
    const float* Wq  = (const float*)d_in[1];
    const float* Wk  = (const float*)d_in[2];
    const float* Wv  = (const float*)d_in[3];
    const float* Wp  = (const float*)d_in[4];
    const float* bp  = (const float*)d_in[5];
    const float* rph = (const float*)d_in[6];
    const float* rpw = (const float*)d_in[7];

    char* ws = (char*)d_ws;
    const size_t MB = 1024 * 1024;
    bf16* Wqt  = (bf16*)(ws + 0 * MB);
    bf16* Wkt  = (bf16*)(ws + 2 * MB);
    bf16* Wvt  = (bf16*)(ws + 4 * MB);
    bf16* Wpt  = (bf16*)(ws + 6 * MB);
    bf16* xt   = (bf16*)(ws + 8 * MB);          // 144 MB, reused as attno
    bf16* kfrb = (bf16*)(ws + 152 * MB);        // 144 MB (frag-ready K)
    bf16* vfrb = (bf16*)(ws + 296 * MB);        // 144 MB (frag-ready V)
    bf16* xp   = (bf16*)(ws + 440 * MB);        // 36 MB
    bf16* qbuf = (bf16*)(ws + 476 * MB);        // 36 MB -> end 512 MB
    bf16* attno = xt;

    transpose_cvt<<<dim3(32, 32, 1), 256, 0, stream>>>(Wq, Wqt, 1024, 1024, 0, 0);
    transpose_cvt<<<dim3(32, 32, 1), 256, 0, stream>>>(Wk, Wkt, 1024, 1024, 0, 0);
    transpose_cvt<<<dim3(32, 32, 1), 256, 0, stream>>>(Wv, Wvt, 1024, 1024, 0, 0);
    transpose_cvt<<<dim3(32, 32, 1), 256, 0, stream>>>(Wp, Wpt, 1024, 1024, 0, 0);
    transpose_cvt<<<dim3(18, 32, 128), 256, 0, stream>>>(
        x, xt, 1024, 576, (size_t)1024 * 576, (size_t)576 * 1024);
    pool_kernel<<<dim3(B_ * QN), 256, 0, stream>>>(xt, xp);
    gemm_nt<3><<<dim3(576, 8), 256, 0, stream>>>(xt, Wkt, kfrb, nullptr);
    gemm_nt<4><<<dim3(8, 576), 256, 0, stream>>>(Wvt, xt, vfrb, nullptr);
    gemm_nt<0><<<dim3(144, 8), 256, 0, stream>>>(xp, Wqt, qbuf, nullptr);
    attn_kernel<<<dim3(B_ * NH), 576, 0, stream>>>(qbuf, kfrb, vfrb, rph, rpw, attno);
    gemm_nt<2><<<dim3(8, 144), 256, 0, stream>>>(Wpt, attno, d_out, bp);
}